// Round 9
// baseline (1597.739 us; speedup 1.0000x reference)
//
#include <hip/hip_runtime.h>
#include <hip/hip_bf16.h>

#define BATCH 128
#define SEQ   256
#define EMB   256
#define HID   512
#define NCLS  50257

typedef unsigned short u16;
typedef unsigned long long u64;
typedef __attribute__((ext_vector_type(8))) short short8;
typedef __attribute__((ext_vector_type(4))) short s16x4;
typedef __attribute__((ext_vector_type(4))) float f32x4;
typedef __attribute__((ext_vector_type(4))) int   i32x4;

__device__ __forceinline__ u16 f2bf(float f) {
    unsigned x = __builtin_bit_cast(unsigned, f);
    x += 0x7FFFu + ((x >> 16) & 1u);
    return (u16)(x >> 16);
}
__device__ __forceinline__ float sigm(float x) { return 1.f / (1.f + __expf(-x)); }
__device__ __forceinline__ float tanh_(float x) {
    x = fminf(15.f, fmaxf(-15.f, x));
    float e = __expf(2.f * x);
    return (e - 1.f) / (e + 1.f);
}
__device__ __forceinline__ f32x4 zero4() { f32x4 v; v[0]=0.f; v[1]=0.f; v[2]=0.f; v[3]=0.f; return v; }

// ---------------------------------------------------------------------------
// Fused LSTM recurrence — r4's PROVEN flag protocol, latency-hidden:
//  - per-WAVE flags (wave vmcnt ack -> flag store; no producer barrier)
//  - flag loads prefetched before phases A/B (poll RTT hidden)
//  - H loads issued before the x@Wx MFMAs (load RTT hidden under compute)
//  - all protocol traffic via __hip_atomic_* SYSTEM scope (sc0 sc1,
//    compiler-tracked; no hand-asm results live across C++ control flow)
// Barriers: 2/step. sync1: HA staged -> MFMA; sync2: pre published -> gate.
// LDS hazard audit under this order: Ebuf[cur] written at A(t-1), read at
// B(t): sync1(t-1)+sync2(t-1) intervene. HA written at C(t) vs MFMA reads
// at C(t-1): sync2(t-1) intervenes. pre written at D(t) vs reads at E(t-1):
// sync1(t) intervenes. Cst: per-thread exclusive.
// Liveness: poll guard-bounded; flag(t+1) published unconditionally at end
// of step t after a per-wave vmcnt(0) drain (vmcnt covers all 64 lanes'
// stores) -> no circular wait, same ordering argument as passing r4.
// Hbuf (u32): buf(2) x row(128) x slot(256); flags: 512 u32 (bc,cc,wave).
// ---------------------------------------------------------------------------
__global__ __launch_bounds__(256, 1) void rnn_kernel(
    const int* __restrict__ X, const float* __restrict__ Cemb,
    const float* __restrict__ Wxi, const float* __restrict__ Wxf,
    const float* __restrict__ Wxo, const float* __restrict__ Wxc,
    const float* __restrict__ Whi, const float* __restrict__ Whf,
    const float* __restrict__ Who, const float* __restrict__ Whc,
    const float* __restrict__ bi, const float* __restrict__ bfv,
    const float* __restrict__ bo, const float* __restrict__ bcv,
    unsigned* __restrict__ Hbuf, unsigned* __restrict__ flags)
{
    __shared__ __align__(16) char smem[76032];
    u16*   HA  = (u16*)smem;
    float* pre = (float*)(smem + 65536);
    float* Cst = (float*)(smem + 73984);

    const int wg = blockIdx.x;
    const int bc = wg >> 5, cc = wg & 31, b0 = bc * 32;
    const int tid = threadIdx.x, lane = tid & 63, wave = tid >> 6;
    const int pb = tid >> 3, pp = tid & 7;
    const int c0 = pp << 1, c1 = c0 + 1;

    const float* WxA[4] = {Wxi, Wxf, Wxo, Wxc};
    const float* WhA[4] = {Whi, Whf, Who, Whc};

    const float bi0 = bi [cc * 16 + c0], bi1 = bi [cc * 16 + c1];
    const float bf0 = bfv[cc * 16 + c0], bf1 = bfv[cc * 16 + c1];
    const float bo0 = bo [cc * 16 + c0], bo1 = bo [cc * 16 + c1];
    const float bc0 = bcv[cc * 16 + c0], bc1 = bcv[cc * 16 + c1];

    // ---- one-time: W_x slice [256 k][16 n] (f32 -> bf16) -> bregX ----
    short8 bregX[8];
    {
        const float* Wx = WxA[wave];
        u16* dst = HA + wave * 4096;
#pragma unroll
        for (int it = 0; it < 16; ++it) {
            int e = it * 256 + lane * 4;
            int k = e >> 4, cq = (e & 15) >> 2;
            f32x4 v = *(const f32x4*)(Wx + (size_t)k * HID + cc * 16 + cq * 4);
            s16x4 s;
#pragma unroll
            for (int j = 0; j < 4; ++j) s[j] = (short)f2bf(v[j]);
            *(s16x4*)(dst + k * 16 + cq * 4) = s;
        }
    }
    __syncthreads();
    {
        const u16* tile = HA + wave * 4096;
#pragma unroll
        for (int ks = 0; ks < 8; ++ks) {
            short8 v;
#pragma unroll
            for (int i = 0; i < 8; ++i)
                v[i] = (short)tile[(ks * 32 + (lane >> 4) * 8 + i) * 16 + (lane & 15)];
            bregX[ks] = v;
        }
    }
    __syncthreads();

    // ---- one-time: W_h slice [512 k][16 n] per gate -> bregH (2 passes) ----
    short8 bregH[16];
    for (int pass = 0; pass < 2; ++pass) {
        for (int gi = 0; gi < 2; ++gi) {
            const float* W = WhA[2 * pass + gi];
#pragma unroll
            for (int it = 0; it < 8; ++it) {
                int e = it * 1024 + tid * 4;
                int k = e >> 4, cq = (e & 15) >> 2;
                f32x4 v = *(const f32x4*)(W + (size_t)k * HID + cc * 16 + cq * 4);
                s16x4 s;
#pragma unroll
                for (int j = 0; j < 4; ++j) s[j] = (short)f2bf(v[j]);
                *(s16x4*)(HA + gi * 8192 + k * 16 + cq * 4) = s;
            }
        }
        __syncthreads();
        if ((wave >> 1) == pass) {
            const u16* tile = HA + (wave & 1) * 8192;
#pragma unroll
            for (int ks = 0; ks < 16; ++ks) {
                short8 v;
#pragma unroll
                for (int i = 0; i < 8; ++i)
                    v[i] = (short)tile[(ks * 32 + (lane >> 4) * 8 + i) * 16 + (lane & 15)];
                bregH[ks] = v;
            }
        }
        __syncthreads();
    }

    // ---- Cst = 0, stage E_0 into buf 0 ----
    for (int i = tid; i < 512; i += 256) Cst[i] = 0.f;
    {
        int row = tid >> 3, seg = tid & 7;
        int tok = X[(b0 + row) * SEQ + 0];
        const float* src = Cemb + (size_t)tok * EMB + seg * 32;
        char* eb = smem + 32768;
#pragma unroll
        for (int i = 0; i < 4; ++i) {
            f32x4 a = *(const f32x4*)(src + i * 8);
            f32x4 b = *(const f32x4*)(src + i * 8 + 4);
            short8 v;
#pragma unroll
            for (int j = 0; j < 4; ++j) { v[j] = (short)f2bf(a[j]); v[4 + j] = (short)f2bf(b[j]); }
            int off = row * 512 + ((seg * 64 + i * 16) ^ ((row & 7) << 4));
            *(short8*)(eb + off) = v;
        }
    }
    __syncthreads();

    for (int t = 0; t < SEQ; ++t) {
        const int cur = t & 1, nxt = cur ^ 1;
        const unsigned target = (unsigned)t;

        // C0: prefetch this bc's 128 per-wave flags (2 per lane);
        // the wait sinks to first use (after A) -> RTT hidden.
        unsigned f0 = target, f1 = target;
        if (t > 0) {
            f0 = __hip_atomic_load(flags + bc * 128 + lane,
                                   __ATOMIC_RELAXED, __HIP_MEMORY_SCOPE_SYSTEM);
            f1 = __hip_atomic_load(flags + bc * 128 + 64 + lane,
                                   __ATOMIC_RELAXED, __HIP_MEMORY_SCOPE_SYSTEM);
        }

        // A: prefetch E_{t+1} into Ebuf[nxt] (L2-resident)
        {
            int tp = (t + 1 < SEQ) ? (t + 1) : t;
            int row = tid >> 3, seg = tid & 7;
            int tok = X[(b0 + row) * SEQ + tp];
            const float* src = Cemb + (size_t)tok * EMB + seg * 32;
            char* eb = smem + 32768 + nxt * 16384;
#pragma unroll
            for (int i = 0; i < 4; ++i) {
                f32x4 a = *(const f32x4*)(src + i * 8);
                f32x4 b = *(const f32x4*)(src + i * 8 + 4);
                short8 v;
#pragma unroll
                for (int j = 0; j < 4; ++j) { v[j] = (short)f2bf(a[j]); v[4 + j] = (short)f2bf(b[j]); }
                int off = row * 512 + ((seg * 64 + i * 16) ^ ((row & 7) << 4));
                *(short8*)(eb + off) = v;
            }
        }

        // Check flags (likely ready) and ISSUE H loads before phase B.
        u64 hs[16];
        if (t > 0) {
            int guard = 0;
            while (!__all(f0 >= target && f1 >= target)) {
                if (++guard > (1 << 15)) break;        // safety: never hang
                f0 = __hip_atomic_load(flags + bc * 128 + lane,
                                       __ATOMIC_RELAXED, __HIP_MEMORY_SCOPE_SYSTEM);
                f1 = __hip_atomic_load(flags + bc * 128 + 64 + lane,
                                       __ATOMIC_RELAXED, __HIP_MEMORY_SCOPE_SYSTEM);
            }
            const u64* Hs = (const u64*)(Hbuf + cur * 32768);
#pragma unroll
            for (int i = 0; i < 8; ++i) {
                const u64* p = Hs + (size_t)(b0 + 4 * i + wave) * 128 + lane * 2;
                hs[2 * i]     = __hip_atomic_load(p,     __ATOMIC_RELAXED, __HIP_MEMORY_SCOPE_SYSTEM);
                hs[2 * i + 1] = __hip_atomic_load(p + 1, __ATOMIC_RELAXED, __HIP_MEMORY_SCOPE_SYSTEM);
            }
        }

        // B: x @ W_x{gate} (Ebuf[cur]) — overlaps the H-load latency
        f32x4 acc0 = zero4(), acc1 = zero4();
        {
            const char* eb = smem + 32768 + cur * 16384;
            int r0 = lane & 15, r1 = 16 + r0, sw = (r0 & 7) << 4;
#pragma unroll
            for (int ks = 0; ks < 8; ++ks) {
                int inner = ks * 64 + (lane >> 4) * 16;
                short8 a0 = *(const short8*)(eb + r0 * 512 + (inner ^ sw));
                short8 a1 = *(const short8*)(eb + r1 * 512 + (inner ^ sw));
                acc0 = __builtin_amdgcn_mfma_f32_16x16x32_bf16(a0, bregX[ks], acc0, 0, 0, 0);
                acc1 = __builtin_amdgcn_mfma_f32_16x16x32_bf16(a1, bregX[ks], acc1, 0, 0, 0);
            }
        }

        // C: stage H into HA (swizzled), sync1, H @ W_h{gate}
        if (t > 0) {
#pragma unroll
            for (int i = 0; i < 8; ++i) {
                int b = 4 * i + wave;
                i32x4 packs;
                packs[0] = (int)(unsigned)(hs[2 * i] & 0xffffffffu);
                packs[1] = (int)(unsigned)(hs[2 * i] >> 32);
                packs[2] = (int)(unsigned)(hs[2 * i + 1] & 0xffffffffu);
                packs[3] = (int)(unsigned)(hs[2 * i + 1] >> 32);
                int off = b * 1024 + ((lane * 16) ^ ((b & 7) << 4));
                *(short8*)((char*)HA + off) = __builtin_bit_cast(short8, packs);
            }
            __syncthreads();                                   // sync1

            int r0 = lane & 15, r1 = 16 + r0, sw = (r0 & 7) << 4;
#pragma unroll
            for (int ks = 0; ks < 16; ++ks) {
                int inner = ks * 64 + (lane >> 4) * 16;
                short8 a0 = *(const short8*)((const char*)HA + r0 * 1024 + (inner ^ sw));
                short8 a1 = *(const short8*)((const char*)HA + r1 * 1024 + (inner ^ sw));
                acc0 = __builtin_amdgcn_mfma_f32_16x16x32_bf16(a0, bregH[ks], acc0, 0, 0, 0);
                acc1 = __builtin_amdgcn_mfma_f32_16x16x32_bf16(a1, bregH[ks], acc1, 0, 0, 0);
            }
        }

        // D: publish pre-activations (D layout: col=lane&15, row=(lane>>4)*4+r)
        {
            int n = wave * 16 + (lane & 15);
#pragma unroll
            for (int r = 0; r < 4; ++r) {
                pre[n * 33 + (lane >> 4) * 4 + r]      = acc0[r];
                pre[n * 33 + 16 + (lane >> 4) * 4 + r] = acc1[r];
            }
        }
        __syncthreads();                                       // sync2

        // E: gate math + H store (write-through) + per-wave flag release
        {
            float pi0 = pre[(0  + c0) * 33 + pb] + bi0;
            float pi1 = pre[(0  + c1) * 33 + pb] + bi1;
            float pf0 = pre[(16 + c0) * 33 + pb] + bf0;
            float pf1 = pre[(16 + c1) * 33 + pb] + bf1;
            float po0 = pre[(32 + c0) * 33 + pb] + bo0;
            float po1 = pre[(32 + c1) * 33 + pb] + bo1;
            float pc0 = pre[(48 + c0) * 33 + pb] + bc0;
            float pc1 = pre[(48 + c1) * 33 + pb] + bc1;
            float I0 = sigm(pi0), F0 = sigm(pf0), O0 = sigm(po0), T0 = tanh_(pc0);
            float I1 = sigm(pi1), F1 = sigm(pf1), O1 = sigm(po1), T1 = tanh_(pc1);
            float Cn0 = F0 * Cst[pb * 16 + c0] + I0 * T0;  Cst[pb * 16 + c0] = Cn0;
            float Cn1 = F1 * Cst[pb * 16 + c1] + I1 * T1;  Cst[pb * 16 + c1] = Cn1;
            float H0 = O0 * tanh_(Cn0), H1 = O1 * tanh_(Cn1);
            unsigned pack = (unsigned)f2bf(H0) | ((unsigned)f2bf(H1) << 16);
            __hip_atomic_store(Hbuf + nxt * 32768 + (b0 + pb) * 256 + cc * 8 + pp,
                               pack, __ATOMIC_RELAXED, __HIP_MEMORY_SCOPE_SYSTEM);
        }
        // wave-level ack of this wave's 64 H stores, then its flag
        asm volatile("s_waitcnt vmcnt(0)" ::: "memory");
        if ((tid & 63) == 0) {
            __hip_atomic_store(flags + bc * 128 + cc * 4 + wave, (unsigned)(t + 1),
                               __ATOMIC_RELAXED, __HIP_MEMORY_SCOPE_SYSTEM);
        }
    }
}

// ---------------------------------------------------------------------------
// logits[128][50257] = H_final @ W_hq + b_q. H_final = Hbuf buf0 (bf16 view).
// Verbatim r4 proj (proven): plain loads are safe because rnn's sc0 sc1
// traffic never allocates Hbuf lines into L2.
// ---------------------------------------------------------------------------
__global__ __launch_bounds__(256) void proj_kernel(
    const u16* __restrict__ Hfin, const float* __restrict__ Whq,
    const float* __restrict__ bq, float* __restrict__ out)
{
    __shared__ __align__(16) u16 Alds[128 * 256];
    const int n0   = blockIdx.x * 128;
    const int tid  = threadIdx.x;
    const int lane = tid & 63;
    const int wave = tid >> 6;

    f32x4 acc[8][2];
#pragma unroll
    for (int m = 0; m < 8; ++m) { acc[m][0] = zero4(); acc[m][1] = zero4(); }

    for (int half = 0; half < 2; ++half) {
        int k0 = half * 256;
        {
            int row = tid >> 1, hh = tid & 1;
            const u16* src = Hfin + row * HID + k0 + hh * 128;
#pragma unroll
            for (int i = 0; i < 16; ++i) {
                short8 v = *(const short8*)(src + i * 8);
                int byte_off = row * 512 + ((hh * 256 + i * 16) ^ ((row & 7) << 4));
                *(short8*)((char*)Alds + byte_off) = v;
            }
        }
        __syncthreads();

        const int col0 = wave * 32;
        for (int ks = 0; ks < 8; ++ks) {
            short8 bfrag[2];
#pragma unroll
            for (int nf = 0; nf < 2; ++nf) {
                int n  = n0 + col0 + nf * 16 + (lane & 15);
                int nc = (n < NCLS) ? n : (NCLS - 1);
                int kb = k0 + ks * 32 + (lane >> 4) * 8;
                short8 v;
#pragma unroll
                for (int j = 0; j < 8; ++j)
                    v[j] = (short)f2bf(Whq[(size_t)(kb + j) * NCLS + nc]);
                bfrag[nf] = v;
            }
#pragma unroll
            for (int mf = 0; mf < 8; ++mf) {
                int row = mf * 16 + (lane & 15);
                int byte_off = row * 512 + ((ks * 64 + (lane >> 4) * 16) ^ ((row & 7) << 4));
                short8 a = *(const short8*)((const char*)Alds + byte_off);
                acc[mf][0] = __builtin_amdgcn_mfma_f32_16x16x32_bf16(a, bfrag[0], acc[mf][0], 0, 0, 0);
                acc[mf][1] = __builtin_amdgcn_mfma_f32_16x16x32_bf16(a, bfrag[1], acc[mf][1], 0, 0, 0);
            }
        }
        __syncthreads();
    }
#pragma unroll
    for (int nf = 0; nf < 2; ++nf) {
        int col = wave * 32 + nf * 16 + (lane & 15);
        int n = n0 + col;
        if (n < NCLS) {
            float bias = bq[n];
#pragma unroll
            for (int mf = 0; mf < 8; ++mf)
#pragma unroll
                for (int r = 0; r < 4; ++r) {
                    int b = mf * 16 + (lane >> 4) * 4 + r;
                    out[(size_t)b * NCLS + n] = acc[mf][nf][r] + bias;
                }
        }
    }
}

// ---------------------------------------------------------------------------
extern "C" void kernel_launch(void* const* d_in, const int* in_sizes, int n_in,
                              void* d_out, int out_size, void* d_ws, size_t ws_size,
                              hipStream_t stream)
{
    (void)in_sizes; (void)n_in; (void)out_size; (void)ws_size;
    const int*   X    = (const int*)d_in[0];
    const float* Cemb = (const float*)d_in[1];
    const float* Wxi  = (const float*)d_in[2];
    const float* Wxf  = (const float*)d_in[3];
    const float* Wxo  = (const float*)d_in[4];
    const float* Wxc  = (const float*)d_in[5];
    const float* Whi  = (const float*)d_in[6];
    const float* Whf  = (const float*)d_in[7];
    const float* Who  = (const float*)d_in[8];
    const float* Whc  = (const float*)d_in[9];
    const float* bi   = (const float*)d_in[10];
    const float* bfv  = (const float*)d_in[11];
    const float* bo   = (const float*)d_in[12];
    const float* bcv  = (const float*)d_in[13];
    const float* Whq  = (const float*)d_in[14];
    const float* bq   = (const float*)d_in[15];
    float* out = (float*)d_out;

    unsigned* Hbuf  = (unsigned*)d_ws;                    // 262,144 B
    unsigned* flags = (unsigned*)((char*)d_ws + 262144);  // 512 * 4 = 2,048 B

    hipMemsetAsync(flags, 0, 2048, stream);
    void* args[] = {(void*)&X, (void*)&Cemb,
                    (void*)&Wxi, (void*)&Wxf, (void*)&Wxo, (void*)&Wxc,
                    (void*)&Whi, (void*)&Whf, (void*)&Who, (void*)&Whc,
                    (void*)&bi, (void*)&bfv, (void*)&bo, (void*)&bcv,
                    (void*)&Hbuf, (void*)&flags};
    hipLaunchCooperativeKernel(reinterpret_cast<void*>(rnn_kernel),
                               dim3(128), dim3(256), args, 0, stream);
    proj_kernel<<<(NCLS + 127) / 128, 256, 0, stream>>>((const u16*)d_ws, Whq, bq, out);
}

// Round 10
// 664.507 us; speedup vs baseline: 2.4044x; 2.4044x over previous
//
#include <hip/hip_runtime.h>
#include <hip/hip_bf16.h>

#define BATCH 128
#define SEQ   256
#define EMB   256
#define HID   512
#define NCLS  50257

typedef unsigned short u16;
typedef unsigned long long u64;
typedef __attribute__((ext_vector_type(8))) short short8;
typedef __attribute__((ext_vector_type(4))) short s16x4;
typedef __attribute__((ext_vector_type(4))) float f32x4;
typedef __attribute__((ext_vector_type(4))) int   i32x4;

__device__ __forceinline__ u16 f2bf(float f) {
    unsigned x = __builtin_bit_cast(unsigned, f);
    x += 0x7FFFu + ((x >> 16) & 1u);
    return (u16)(x >> 16);
}
__device__ __forceinline__ float sigm(float x) { return 1.f / (1.f + __expf(-x)); }
__device__ __forceinline__ float tanh_(float x) {
    x = fminf(15.f, fmaxf(-15.f, x));
    float e = __expf(2.f * x);
    return (e - 1.f) / (e + 1.f);
}
__device__ __forceinline__ f32x4 zero4() { f32x4 v; v[0]=0.f; v[1]=0.f; v[2]=0.f; v[3]=0.f; return v; }

// ---------------------------------------------------------------------------
// LSTM recurrence, 256 wgs (1/CU): wg -> (bc=wg&7, cc=wg>>3). Group bc = 32
// wgs owning batch rows [16*bc,+16), all 512 H-cols (16 per wg). One gate per
// wave; W slices in VGPRs. Protocol = r4's PROVEN flag scheme; cache policy
// selected at runtime: if every bc group is XCD-pure (verified via
// HW_REG_XCC_ID exchange + 2-phase global agreement), H/flag ops use sc0 only
// (XCD-local L2 coherence, ~6x lower RTT); else sc0 sc1 (L3, r4 semantics).
// Garbage/unknown hwreg values or any disagreement => slow path (safe).
// Final H -> separate Hfin region, always sc0 sc1 (never L2-dirty => no
// stale-writeback clobber); end-of-kernel __threadfence() (wbl2+inv) cleans
// L2 dirt for graph replays. proj reads Hfin via system-scope atomics.
// LDS: [0,16384) HA [16][1024B] swz (weight-staging scratch uses [0,32768));
// [16384,24576) E0; [24576,32768) E1; [32768,37120) pre[64][17]f32;
// [37120,38144) Cst[16][16]f32.
// ---------------------------------------------------------------------------
__global__ __launch_bounds__(256, 1) void rnn_kernel(
    const int* __restrict__ X, const float* __restrict__ Cemb,
    const float* __restrict__ Wxi, const float* __restrict__ Wxf,
    const float* __restrict__ Wxo, const float* __restrict__ Wxc,
    const float* __restrict__ Whi, const float* __restrict__ Whf,
    const float* __restrict__ Who, const float* __restrict__ Whc,
    const float* __restrict__ bi, const float* __restrict__ bfv,
    const float* __restrict__ bo, const float* __restrict__ bcv,
    u16* __restrict__ Hbuf, u16* __restrict__ Hfin,
    unsigned* __restrict__ flags, unsigned* __restrict__ xcc,
    unsigned* __restrict__ vbuf)
{
    __shared__ __align__(16) char smem[38144];
    u16*   HA  = (u16*)smem;
    float* pre = (float*)(smem + 32768);
    float* Cst = (float*)(smem + 37120);

    const int wg = blockIdx.x;
    const int bc = wg & 7, cc = wg >> 3, b0 = bc * 16;
    const int tid = threadIdx.x, lane = tid & 63, wave = tid >> 6;
    const int pb = tid >> 4, ec = tid & 15;

    // ===== XCD discovery + global verdict (one-time) =====
    unsigned* sh = (unsigned*)smem;
    if (tid == 0) {
        unsigned raw;
        asm volatile("s_getreg_b32 %0, hwreg(HW_REG_XCC_ID)" : "=s"(raw));
        __hip_atomic_store(xcc + wg, raw & 0xFFu, __ATOMIC_RELAXED, __HIP_MEMORY_SCOPE_SYSTEM);
    }
    {
        unsigned v; int g = 0;
        do { v = __hip_atomic_load(xcc + tid, __ATOMIC_RELAXED, __HIP_MEMORY_SCOPE_SYSTEM); }
        while (v == 0xFFFFFFFFu && ++g < (1 << 22));
        sh[tid] = v;
    }
    __syncthreads();
    if (tid == 0) {
        int ok = 1;
        for (int i = 0; i < 256; ++i) if (sh[i] != sh[i & 7]) { ok = 0; break; }
        if (ok) {
            unsigned m = 0;
            for (int g8 = 0; g8 < 8; ++g8) {
                unsigned r = sh[g8];
                if (r > 7u || ((m >> r) & 1u)) { ok = 0; break; }
                m |= 1u << r;
            }
        }
        sh[256] = (unsigned)ok;
    }
    __syncthreads();
    const unsigned myok = sh[256];
    __syncthreads();
    if (tid == 0)
        __hip_atomic_store(vbuf + wg, myok, __ATOMIC_RELAXED, __HIP_MEMORY_SCOPE_SYSTEM);
    {
        unsigned v; int g = 0;
        do { v = __hip_atomic_load(vbuf + tid, __ATOMIC_RELAXED, __HIP_MEMORY_SCOPE_SYSTEM); }
        while (v == 0xFFFFFFFFu && ++g < (1 << 22));
        sh[tid] = v;
    }
    __syncthreads();
    if (tid == 0) {
        int ok = 1;
        for (int i = 0; i < 256; ++i) if (sh[i] != 1u) { ok = 0; break; }
        sh[256] = (unsigned)ok;
    }
    __syncthreads();
    const bool FAST = sh[256] != 0;
    __syncthreads();

    const float* WxA[4] = {Wxi, Wxf, Wxo, Wxc};
    const float* WhA[4] = {Whi, Whf, Who, Whc};

    const float bias_i = bi [cc * 16 + ec];
    const float bias_f = bfv[cc * 16 + ec];
    const float bias_o = bo [cc * 16 + ec];
    const float bias_c = bcv[cc * 16 + ec];

    // ---- one-time: W_x slice [256 k][16 n] (f32 -> bf16) -> bregX ----
    short8 bregX[8];
    {
        const float* Wx = WxA[wave];
        u16* dst = HA + wave * 4096;
#pragma unroll
        for (int it = 0; it < 16; ++it) {
            int e = it * 256 + lane * 4;
            int k = e >> 4, cq = (e & 15) >> 2;
            f32x4 v = *(const f32x4*)(Wx + (size_t)k * HID + cc * 16 + cq * 4);
            s16x4 s;
#pragma unroll
            for (int j = 0; j < 4; ++j) s[j] = (short)f2bf(v[j]);
            *(s16x4*)(dst + k * 16 + cq * 4) = s;
        }
    }
    __syncthreads();
    {
        const u16* tile = HA + wave * 4096;
#pragma unroll
        for (int ks = 0; ks < 8; ++ks) {
            short8 v;
#pragma unroll
            for (int i = 0; i < 8; ++i)
                v[i] = (short)tile[(ks * 32 + (lane >> 4) * 8 + i) * 16 + (lane & 15)];
            bregX[ks] = v;
        }
    }
    __syncthreads();

    // ---- one-time: W_h slice [512 k][16 n] per gate -> bregH (2 passes) ----
    short8 bregH[16];
    for (int pass = 0; pass < 2; ++pass) {
        for (int gi = 0; gi < 2; ++gi) {
            const float* W = WhA[2 * pass + gi];
#pragma unroll
            for (int it = 0; it < 8; ++it) {
                int e = it * 1024 + tid * 4;
                int k = e >> 4, cq = (e & 15) >> 2;
                f32x4 v = *(const f32x4*)(W + (size_t)k * HID + cc * 16 + cq * 4);
                s16x4 s;
#pragma unroll
                for (int j = 0; j < 4; ++j) s[j] = (short)f2bf(v[j]);
                *(s16x4*)(HA + gi * 8192 + k * 16 + cq * 4) = s;
            }
        }
        __syncthreads();
        if ((wave >> 1) == pass) {
            const u16* tile = HA + (wave & 1) * 8192;
#pragma unroll
            for (int ks = 0; ks < 16; ++ks) {
                short8 v;
#pragma unroll
                for (int i = 0; i < 8; ++i)
                    v[i] = (short)tile[(ks * 32 + (lane >> 4) * 8 + i) * 16 + (lane & 15)];
                bregH[ks] = v;
            }
        }
        __syncthreads();
    }

    // ---- Cst = 0, stage E_0 into buf 0 ----
    Cst[tid] = 0.f;
    {
        int row = tid >> 4, seg = tid & 15;
        int tok = X[(b0 + row) * SEQ + 0];
        const float* src = Cemb + (size_t)tok * EMB + seg * 16;
        char* eb = smem + 16384;
        f32x4 a0 = *(const f32x4*)(src);
        f32x4 a1 = *(const f32x4*)(src + 4);
        f32x4 a2 = *(const f32x4*)(src + 8);
        f32x4 a3 = *(const f32x4*)(src + 12);
        short8 v0, v1;
#pragma unroll
        for (int j = 0; j < 4; ++j) {
            v0[j] = (short)f2bf(a0[j]); v0[4 + j] = (short)f2bf(a1[j]);
            v1[j] = (short)f2bf(a2[j]); v1[4 + j] = (short)f2bf(a3[j]);
        }
        int sw = (row & 7) << 4;
        *(short8*)(eb + row * 512 + ((seg * 32)      ^ sw)) = v0;
        *(short8*)(eb + row * 512 + ((seg * 32 + 16) ^ sw)) = v1;
    }
    __syncthreads();

    for (int t = 0; t < SEQ; ++t) {
        const int cur = t & 1, nxt = cur ^ 1;

        // A: prefetch E_{t+1} into Ebuf[nxt]
        {
            int tp = (t + 1 < SEQ) ? (t + 1) : t;
            int row = tid >> 4, seg = tid & 15;
            int tok = X[(b0 + row) * SEQ + tp];
            const float* src = Cemb + (size_t)tok * EMB + seg * 16;
            char* eb = smem + 16384 + nxt * 8192;
            f32x4 a0 = *(const f32x4*)(src);
            f32x4 a1 = *(const f32x4*)(src + 4);
            f32x4 a2 = *(const f32x4*)(src + 8);
            f32x4 a3 = *(const f32x4*)(src + 12);
            short8 v0, v1;
#pragma unroll
            for (int j = 0; j < 4; ++j) {
                v0[j] = (short)f2bf(a0[j]); v0[4 + j] = (short)f2bf(a1[j]);
                v1[j] = (short)f2bf(a2[j]); v1[4 + j] = (short)f2bf(a3[j]);
            }
            int sw = (row & 7) << 4;
            *(short8*)(eb + row * 512 + ((seg * 32)      ^ sw)) = v0;
            *(short8*)(eb + row * 512 + ((seg * 32 + 16) ^ sw)) = v1;
        }

        // B: x @ W_x{gate} (Ebuf[cur])
        f32x4 acc0 = zero4();
        {
            const char* eb = smem + 16384 + cur * 8192;
            int r0 = lane & 15, sw = (r0 & 7) << 4;
#pragma unroll
            for (int ks = 0; ks < 8; ++ks) {
                int inner = ks * 64 + (lane >> 4) * 16;
                short8 a0 = *(const short8*)(eb + r0 * 512 + (inner ^ sw));
                acc0 = __builtin_amdgcn_mfma_f32_16x16x32_bf16(a0, bregX[ks], acc0, 0, 0, 0);
            }
        }

        // C: poll flags (wave0), stage H, MFMA-H
        if (t > 0) {
            if (wave == 0) {
                const unsigned* fp = flags + bc * 32 + (lane & 31);
                unsigned target = (unsigned)t;
                int guard = 0; unsigned v = 0;
                if (FAST) {
                    do { asm volatile("global_load_dword %0, %1, off sc0\n\ts_waitcnt vmcnt(0)"
                                      : "=v"(v) : "v"(fp) : "memory");
                    } while (!__all(v >= target) && ++guard < (1 << 15));
                } else {
                    do { asm volatile("global_load_dword %0, %1, off sc0 sc1\n\ts_waitcnt vmcnt(0)"
                                      : "=v"(v) : "v"(fp) : "memory");
                    } while (!__all(v >= target) && ++guard < (1 << 15));
                }
            }
            __syncthreads();

            const u16* Hs = Hbuf + cur * 65536;
            i32x4 h[4];
#pragma unroll
            for (int i = 0; i < 4; ++i) {
                int elem = i * 2048 + tid * 8;
                int row = elem >> 9, k = elem & 511;
                const u16* p = Hs + (b0 + row) * 512 + k;
                if (FAST) asm volatile("global_load_dwordx4 %0, %1, off sc0" : "=v"(h[i]) : "v"(p));
                else      asm volatile("global_load_dwordx4 %0, %1, off sc0 sc1" : "=v"(h[i]) : "v"(p));
            }
            asm volatile("s_waitcnt vmcnt(0)" ::: "memory");
            __builtin_amdgcn_sched_barrier(0);
#pragma unroll
            for (int i = 0; i < 4; ++i) {
                int elem = i * 2048 + tid * 8;
                int row = elem >> 9, k = elem & 511;
                int off = row * 1024 + ((k * 2) ^ ((row & 7) << 4));
                *(short8*)((char*)HA + off) = __builtin_bit_cast(short8, h[i]);
            }
            __syncthreads();                                   // sync1

            int r0 = lane & 15, sw = (r0 & 7) << 4;
#pragma unroll
            for (int ks = 0; ks < 16; ++ks) {
                int inner = ks * 64 + (lane >> 4) * 16;
                short8 a0 = *(const short8*)((const char*)HA + r0 * 1024 + (inner ^ sw));
                acc0 = __builtin_amdgcn_mfma_f32_16x16x32_bf16(a0, bregH[ks], acc0, 0, 0, 0);
            }
        }

        // D: publish pre-activations (col=lane&15, row=(lane>>4)*4+r)
        {
            int n = wave * 16 + (lane & 15);
#pragma unroll
            for (int r = 0; r < 4; ++r)
                pre[n * 17 + (lane >> 4) * 4 + r] = acc0[r];
        }
        __syncthreads();                                       // sync2

        // E: gate math (1 elem/thread) + H store + ack
        {
            float pi = pre[(0  + ec) * 17 + pb] + bias_i;
            float pf = pre[(16 + ec) * 17 + pb] + bias_f;
            float po = pre[(32 + ec) * 17 + pb] + bias_o;
            float pc = pre[(48 + ec) * 17 + pb] + bias_c;
            float I = sigm(pi), F = sigm(pf), O = sigm(po), T = tanh_(pc);
            float Cn = F * Cst[pb * 16 + ec] + I * T;
            Cst[pb * 16 + ec] = Cn;
            unsigned hv = (unsigned)f2bf(O * tanh_(Cn));
            if (t == SEQ - 1) {
                u16* dst = Hfin + (b0 + pb) * 512 + cc * 16 + ec;
                asm volatile("global_store_short %0, %1, off sc0 sc1\n\ts_waitcnt vmcnt(0)"
                             :: "v"(dst), "v"(hv) : "memory");
            } else {
                u16* dst = Hbuf + nxt * 65536 + (b0 + pb) * 512 + cc * 16 + ec;
                if (FAST) asm volatile("global_store_short %0, %1, off sc0\n\ts_waitcnt vmcnt(0)"
                                       :: "v"(dst), "v"(hv) : "memory");
                else      asm volatile("global_store_short %0, %1, off sc0 sc1\n\ts_waitcnt vmcnt(0)"
                                       :: "v"(dst), "v"(hv) : "memory");
            }
        }
        __syncthreads();                                       // all stores acked
        if (tid == 0 && t < SEQ - 1) {
            unsigned* fp = flags + bc * 32 + cc;
            unsigned val = (unsigned)(t + 1);
            if (FAST) asm volatile("global_store_dword %0, %1, off sc0"
                                   :: "v"(fp), "v"(val) : "memory");
            else      asm volatile("global_store_dword %0, %1, off sc0 sc1"
                                   :: "v"(fp), "v"(val) : "memory");
        }
    }

    // clean L2 dirt (fast-path Hbuf/flag lines) so graph replays / other
    // XCDs never see stale writebacks. wbl2+inv per XCD (every XCD hosts wgs).
    __threadfence();
}

// ---------------------------------------------------------------------------
// logits[128][50257] = Hfin @ W_hq + b_q. Hfin read via system-scope atomics
// (always written sc0 sc1 -> L3; bypass any stale L2 lines).
// ---------------------------------------------------------------------------
__global__ __launch_bounds__(256) void proj_kernel(
    const u16* __restrict__ Hfin, const float* __restrict__ Whq,
    const float* __restrict__ bq, float* __restrict__ out)
{
    __shared__ __align__(16) u16 Alds[128 * 256];
    const int n0   = blockIdx.x * 128;
    const int tid  = threadIdx.x;
    const int lane = tid & 63;
    const int wave = tid >> 6;

    f32x4 acc[8][2];
#pragma unroll
    for (int m = 0; m < 8; ++m) { acc[m][0] = zero4(); acc[m][1] = zero4(); }

    const u64* H8 = (const u64*)Hfin;
    for (int half = 0; half < 2; ++half) {
        int k0 = half * 256;
        {
            int row = tid >> 1, hh = tid & 1;
#pragma unroll
            for (int i = 0; i < 16; ++i) {
                int col = k0 + hh * 128 + i * 8;
                size_t idx = (size_t)row * 128 + (col >> 2);
                u64 w0 = __hip_atomic_load(H8 + idx,     __ATOMIC_RELAXED, __HIP_MEMORY_SCOPE_SYSTEM);
                u64 w1 = __hip_atomic_load(H8 + idx + 1, __ATOMIC_RELAXED, __HIP_MEMORY_SCOPE_SYSTEM);
                i32x4 packs;
                packs[0] = (int)(unsigned)(w0 & 0xffffffffu);
                packs[1] = (int)(unsigned)(w0 >> 32);
                packs[2] = (int)(unsigned)(w1 & 0xffffffffu);
                packs[3] = (int)(unsigned)(w1 >> 32);
                int byte_off = row * 512 + ((hh * 256 + i * 16) ^ ((row & 7) << 4));
                *(short8*)((char*)Alds + byte_off) = __builtin_bit_cast(short8, packs);
            }
        }
        __syncthreads();

        const int col0 = wave * 32;
        for (int ks = 0; ks < 8; ++ks) {
            short8 bfrag[2];
#pragma unroll
            for (int nf = 0; nf < 2; ++nf) {
                int n  = n0 + col0 + nf * 16 + (lane & 15);
                int nc = (n < NCLS) ? n : (NCLS - 1);
                int kb = k0 + ks * 32 + (lane >> 4) * 8;
                short8 v;
#pragma unroll
                for (int j = 0; j < 8; ++j)
                    v[j] = (short)f2bf(Whq[(size_t)(kb + j) * NCLS + nc]);
                bfrag[nf] = v;
            }
#pragma unroll
            for (int mf = 0; mf < 8; ++mf) {
                int row = mf * 16 + (lane & 15);
                int byte_off = row * 512 + ((ks * 64 + (lane >> 4) * 16) ^ ((row & 7) << 4));
                short8 a = *(const short8*)((const char*)Alds + byte_off);
                acc[mf][0] = __builtin_amdgcn_mfma_f32_16x16x32_bf16(a, bfrag[0], acc[mf][0], 0, 0, 0);
                acc[mf][1] = __builtin_amdgcn_mfma_f32_16x16x32_bf16(a, bfrag[1], acc[mf][1], 0, 0, 0);
            }
        }
        __syncthreads();
    }
#pragma unroll
    for (int nf = 0; nf < 2; ++nf) {
        int col = wave * 32 + nf * 16 + (lane & 15);
        int n = n0 + col;
        if (n < NCLS) {
            float bias = bq[n];
#pragma unroll
            for (int mf = 0; mf < 8; ++mf)
#pragma unroll
                for (int r = 0; r < 4; ++r) {
                    int b = mf * 16 + (lane >> 4) * 4 + r;
                    out[(size_t)b * NCLS + n] = acc[mf][nf][r] + bias;
                }
        }
    }
}

// ---------------------------------------------------------------------------
extern "C" void kernel_launch(void* const* d_in, const int* in_sizes, int n_in,
                              void* d_out, int out_size, void* d_ws, size_t ws_size,
                              hipStream_t stream)
{
    (void)in_sizes; (void)n_in; (void)out_size; (void)ws_size;
    const int*   X    = (const int*)d_in[0];
    const float* Cemb = (const float*)d_in[1];
    const float* Wxi  = (const float*)d_in[2];
    const float* Wxf  = (const float*)d_in[3];
    const float* Wxo  = (const float*)d_in[4];
    const float* Wxc  = (const float*)d_in[5];
    const float* Whi  = (const float*)d_in[6];
    const float* Whf  = (const float*)d_in[7];
    const float* Who  = (const float*)d_in[8];
    const float* Whc  = (const float*)d_in[9];
    const float* bi   = (const float*)d_in[10];
    const float* bfv  = (const float*)d_in[11];
    const float* bo   = (const float*)d_in[12];
    const float* bcv  = (const float*)d_in[13];
    const float* Whq  = (const float*)d_in[14];
    const float* bq   = (const float*)d_in[15];
    float* out = (float*)d_out;

    char* ws = (char*)d_ws;
    u16*      Hbuf  = (u16*)ws;                         // [0, 262144)
    u16*      Hfin  = (u16*)(ws + 262144);              // [262144, 393216)
    unsigned* flags = (unsigned*)(ws + 393216);         // 1024 B
    unsigned* xcc   = (unsigned*)(ws + 394240);         // 1024 B
    unsigned* vbuf  = (unsigned*)(ws + 395264);         // 1024 B

    hipMemsetAsync(flags, 0, 1024, stream);
    hipMemsetAsync(xcc, 0xFF, 2048, stream);            // xcc + vbuf
    void* args[] = {(void*)&X, (void*)&Cemb,
                    (void*)&Wxi, (void*)&Wxf, (void*)&Wxo, (void*)&Wxc,
                    (void*)&Whi, (void*)&Whf, (void*)&Who, (void*)&Whc,
                    (void*)&bi, (void*)&bfv, (void*)&bo, (void*)&bcv,
                    (void*)&Hbuf, (void*)&Hfin, (void*)&flags,
                    (void*)&xcc, (void*)&vbuf};
    hipLaunchCooperativeKernel(reinterpret_cast<void*>(rnn_kernel),
                               dim3(256), dim3(256), args, 0, stream);
    proj_kernel<<<(NCLS + 127) / 128, 256, 0, stream>>>(Hfin, Whq, bq, out);
}